// Round 4
// baseline (1790.513 us; speedup 1.0000x reference)
//
#include <hip/hip_runtime.h>

#define D 128
#define H 256

typedef _Float16 half8 __attribute__((ext_vector_type(8)));
typedef _Float16 half2v __attribute__((ext_vector_type(2)));
typedef float floatx4 __attribute__((ext_vector_type(4)));

// ---------------- CSR build ----------------
__global__ void hist_kernel(const int* __restrict__ dst, int* __restrict__ cnt, int E){
  int e = blockIdx.x*256 + threadIdx.x;
  if (e < E) atomicAdd(&cnt[dst[e]], 1);
}

__global__ __launch_bounds__(256) void scan_part(const int* __restrict__ cnt,
                                                 int* __restrict__ bsum, int N){
  int base = blockIdx.x*1024;
  int tid = threadIdx.x;
  int idx = base + tid*4;
  int4 v = {0,0,0,0};
  if (idx + 3 < N) v = *(const int4*)(cnt + idx);
  else {
    if (idx   < N) v.x = cnt[idx];
    if (idx+1 < N) v.y = cnt[idx+1];
    if (idx+2 < N) v.z = cnt[idx+2];
    if (idx+3 < N) v.w = cnt[idx+3];
  }
  int s = v.x + v.y + v.z + v.w;
  #pragma unroll
  for (int off = 32; off > 0; off >>= 1) s += __shfl_down(s, off, 64);
  __shared__ int ws[4];
  int lane = tid & 63, wave = tid >> 6;
  if (lane == 0) ws[wave] = s;
  __syncthreads();
  if (tid == 0) bsum[blockIdx.x] = ws[0] + ws[1] + ws[2] + ws[3];
}

__global__ __launch_bounds__(1024) void scan_bsums(const int* __restrict__ bsum,
                                                   int* __restrict__ bbase,
                                                   int* __restrict__ rowptr, int nb, int N){
  __shared__ int sh[1024];
  int tid = threadIdx.x;
  int v = (tid < nb) ? bsum[tid] : 0;
  sh[tid] = v;
  __syncthreads();
  #pragma unroll
  for (int off = 1; off < 1024; off <<= 1){
    int t = 0;
    if (tid >= off) t = sh[tid - off];
    __syncthreads();
    if (tid >= off) sh[tid] += t;
    __syncthreads();
  }
  if (tid < nb) bbase[tid] = sh[tid] - v;
  if (tid == 0) rowptr[N] = sh[1023];
}

__global__ __launch_bounds__(256) void scan_emit(const int* __restrict__ cnt,
                                                 const int* __restrict__ bbase,
                                                 int* __restrict__ rowptr, int N){
  int base = blockIdx.x*1024;
  int tid = threadIdx.x;
  int idx = base + tid*4;
  int4 v = {0,0,0,0};
  if (idx + 3 < N) v = *(const int4*)(cnt + idx);
  else {
    if (idx   < N) v.x = cnt[idx];
    if (idx+1 < N) v.y = cnt[idx+1];
    if (idx+2 < N) v.z = cnt[idx+2];
    if (idx+3 < N) v.w = cnt[idx+3];
  }
  int s = v.x + v.y + v.z + v.w;
  int lane = tid & 63, wave = tid >> 6;
  int incl = s;
  #pragma unroll
  for (int off = 1; off < 64; off <<= 1){
    int t = __shfl_up(incl, off, 64);
    if (lane >= off) incl += t;
  }
  __shared__ int ws[4];
  if (lane == 63) ws[wave] = incl;
  __syncthreads();
  int woff = 0;
  #pragma unroll
  for (int w = 0; w < 4; ++w) if (w < wave) woff += ws[w];
  int off0 = bbase[blockIdx.x] + woff + (incl - s);
  if (idx   < N) rowptr[idx]   = off0;
  if (idx+1 < N) rowptr[idx+1] = off0 + v.x;
  if (idx+2 < N) rowptr[idx+2] = off0 + v.x + v.y;
  if (idx+3 < N) rowptr[idx+3] = off0 + v.x + v.y + v.z;
}

// bucket b (64 nodes) staging cursor starts at rowptr[64b]
__global__ void bcur_init(const int* __restrict__ rowptr, int* __restrict__ bcur, int nbuck){
  int b = blockIdx.x*256 + threadIdx.x;
  if (b < nbuck) bcur[b] = rowptr[b*64];
}

// pass 1: append (pv, dst) into the dst's bucket region of stage (sequential-ish writes)
__global__ void bucket_scatter(const int* __restrict__ src, const int* __restrict__ dst,
                               const int* __restrict__ ea, int* __restrict__ bcur,
                               uint2* __restrict__ stage, int E){
  int e = blockIdx.x*256 + threadIdx.x;
  if (e >= E) return;
  int d = dst[e];
  unsigned pv = ((unsigned)(ea[2*e]*3 + ea[2*e+1]) << 20) | (unsigned)src[e];
  int pos = atomicAdd(&bcur[d >> 6], 1);
  uint2 s; s.x = pv; s.y = (unsigned)d;
  stage[pos] = s;
}

// pass 2: one block per bucket; scatter within a ~4.3 KB L2-resident window
__global__ __launch_bounds__(256) void bucket_emit(const uint2* __restrict__ stage,
                                                   const int* __restrict__ rowptr,
                                                   int* __restrict__ cursor,
                                                   unsigned* __restrict__ packed, int N){
  int b = blockIdx.x;
  int n0 = b*64;
  int n1 = min(n0 + 64, N);
  int beg = rowptr[n0], end = rowptr[n1];
  for (int j = beg + threadIdx.x; j < end; j += 256){
    uint2 s = stage[j];
    int d = (int)s.y;
    int pos = rowptr[d] + atomicAdd(&cursor[d], 1);
    packed[pos] = s.x;
  }
}

// ---------------- input embedding ----------------
__global__ void embed_kernel(const int* __restrict__ x, const float* __restrict__ xemb,
                             _Float16* __restrict__ h, int N){
  int t = blockIdx.x*256 + threadIdx.x;
  if (t >= N*16) return;
  int n = t >> 4, c = (t & 15) * 8;
  int x0 = x[2*n], x1 = x[2*n+1];
  const float* r0 = xemb + (size_t)x0*D + c;
  const float* r1 = xemb + (size_t)(120 + x1)*D + c;
  half8 o;
  #pragma unroll
  for (int j = 0; j < 8; ++j) o[j] = (_Float16)(r0[j] + r1[j]);
  *(half8*)(h + (size_t)n*D + c) = o;
}

// ---------------- per-layer constant tables ----------------
__global__ void prep_tables(const float* __restrict__ etab, const float* __restrict__ gamma,
                            const float* __restrict__ beta, const float* __restrict__ mean,
                            const float* __restrict__ var, const float* __restrict__ b2,
                            float* __restrict__ comb, float* __restrict__ sc, float* __restrict__ sh){
  int l = blockIdx.x, d = threadIdx.x;
  const float* et = etab + (size_t)l*9*D;
  float* cl = comb + (size_t)l*10*D;
  #pragma unroll
  for (int b = 0; b < 3; ++b)
    #pragma unroll
    for (int dd = 0; dd < 3; ++dd)
      cl[(b*3+dd)*D + d] = et[b*D + d] + et[(6+dd)*D + d];
  cl[9*D + d] = et[4*D + d] + et[6*D + d];
  float A = gamma[l*D+d] * rsqrtf(var[l*D+d] + 1e-5f);
  sc[l*D+d] = A;
  sh[l*D+d] = (b2[l*D+d] - mean[l*D+d]) * A + beta[l*D+d];
}

__global__ void cvt_weights(const float* __restrict__ w1, const float* __restrict__ w2,
                            _Float16* __restrict__ w1h, _Float16* __restrict__ w2h, int n){
  int i = blockIdx.x*256 + threadIdx.x;
  if (i < n){ w1h[i] = (_Float16)w1[i]; w2h[i] = (_Float16)w2[i]; }
}

// ---------------- fused layer: gather-aggregate -> LDS -> GEMM1+ReLU -> GEMM2+BN ----------
// 128 rows/block, 512 threads (8 waves). LDS: atile(128x136) aliased into hmid(128x264).
// 67.6 KB + 5 KB cl -> 2 blocks/CU, 16 waves/CU.
__global__ __launch_bounds__(512, 4) void layer_kernel(
    const _Float16* __restrict__ hin, const unsigned* __restrict__ packed,
    const int* __restrict__ rowptr, const float* __restrict__ comb,
    const _Float16* __restrict__ w1h, const _Float16* __restrict__ w2h,
    const float* __restrict__ b1, const float* __restrict__ sc, const float* __restrict__ sh,
    _Float16* __restrict__ hout, float* __restrict__ fout, int N, int relu_out){
  __shared__ __align__(16) char smem[128*264*2];
  _Float16* atile = (_Float16*)smem;   // stride 136 halfs
  _Float16* hmid  = (_Float16*)smem;   // stride 264 halfs (aliased; atile dead after GEMM1)
  __shared__ float cl[10*D];
  int tid = threadIdx.x;
  int wave = tid >> 6, lane = tid & 63;
  int quad = lane >> 4, l15 = lane & 15;
  for (int i = tid; i < 10*D; i += 512) cl[i] = comb[i];
  __syncthreads();
  int r0 = blockIdx.x * 128;
  int c = lane * 2;

  // ---- gather+aggregate: wave handles rows [16w, 16w+16)
  for (int i = 0; i < 16; ++i){
    int row = wave*16 + i;
    int node = r0 + row;          // wave-uniform
    float ax = 0.f, ay = 0.f;
    if (node < N){
      half2v hv = *(const half2v*)(hin + (size_t)node*D + c);
      ax = (float)hv.x + cl[9*D + c];
      ay = (float)hv.y + cl[9*D + c + 1];
      int beg = rowptr[node], end = rowptr[node+1];
      unsigned long long cp = 0;   // 9 codes x 7-bit counters (deg << 127)
      for (int j = beg; j < end; j += 8){
        int m = end - j;           // wave-uniform
        unsigned p[8];
        #pragma unroll
        for (int k = 0; k < 8; ++k) if (k < m) p[k] = packed[j+k];
        half2v v[8];
        #pragma unroll
        for (int k = 0; k < 8; ++k) if (k < m)
          v[k] = *(const half2v*)(hin + (size_t)(p[k] & 0xFFFFFu)*D + c);
        #pragma unroll
        for (int k = 0; k < 8; ++k) if (k < m){
          cp += 1ULL << (7*(int)(p[k] >> 20));
          ax += (float)v[k].x;
          ay += (float)v[k].y;
        }
      }
      #pragma unroll
      for (int cd = 0; cd < 9; ++cd){
        float cnt = (float)(int)((cp >> (7*cd)) & 127);
        ax += cnt * cl[cd*D + c];
        ay += cnt * cl[cd*D + c + 1];
      }
    }
    half2v o; o.x = (_Float16)ax; o.y = (_Float16)ay;
    *(half2v*)(atile + row*136 + c) = o;
  }
  __syncthreads();

  int mh = wave >> 2, nq = wave & 3;

  // ---- GEMM1: C1[128,256] = A x W1^T ; wave (mh,nq): rows 64mh+, cols 64nq+
  floatx4 acc[4][4] = {};
  half8 bcur[4], bnxt[4];
  #pragma unroll
  for (int nt = 0; nt < 4; ++nt)
    bcur[nt] = *(const half8*)(w1h + (size_t)(nq*64 + nt*16 + l15)*D + quad*8);
  #pragma unroll
  for (int ks = 0; ks < 4; ++ks){
    int kk = ks*32 + quad*8;
    if (ks < 3){
      #pragma unroll
      for (int nt = 0; nt < 4; ++nt)
        bnxt[nt] = *(const half8*)(w1h + (size_t)(nq*64 + nt*16 + l15)*D + kk + 32);
    }
    half8 af[4];
    #pragma unroll
    for (int mt = 0; mt < 4; ++mt)
      af[mt] = *(const half8*)(atile + (mh*64 + mt*16 + l15)*136 + kk);
    #pragma unroll
    for (int mt = 0; mt < 4; ++mt)
      #pragma unroll
      for (int nt = 0; nt < 4; ++nt)
        acc[mt][nt] = __builtin_amdgcn_mfma_f32_16x16x32_f16(af[mt], bcur[nt], acc[mt][nt], 0, 0, 0);
    #pragma unroll
    for (int nt = 0; nt < 4; ++nt) bcur[nt] = bnxt[nt];
  }
  __syncthreads();   // all waves done reading atile before hmid overwrites it

  // epilogue 1: +b1, ReLU -> hmid
  #pragma unroll
  for (int nt = 0; nt < 4; ++nt){
    int n = nq*64 + nt*16 + l15;
    float bias = b1[n];
    #pragma unroll
    for (int mt = 0; mt < 4; ++mt)
      #pragma unroll
      for (int r = 0; r < 4; ++r){
        int row = mh*64 + mt*16 + quad*4 + r;   // C/D layout: col=lane&15, row=quad*4+reg
        hmid[row*264 + n] = (_Float16)fmaxf(acc[mt][nt][r] + bias, 0.f);
      }
  }
  __syncthreads();

  // ---- GEMM2: C2[128,128] = hmid x W2^T ; wave (mh,nq): rows 64mh+, cols 32nq+
  floatx4 acc2[4][2] = {};
  half8 gcur[2], gnxt[2];
  #pragma unroll
  for (int nt = 0; nt < 2; ++nt)
    gcur[nt] = *(const half8*)(w2h + (size_t)(nq*32 + nt*16 + l15)*H + quad*8);
  #pragma unroll
  for (int ks = 0; ks < 8; ++ks){
    int kk = ks*32 + quad*8;
    if (ks < 7){
      #pragma unroll
      for (int nt = 0; nt < 2; ++nt)
        gnxt[nt] = *(const half8*)(w2h + (size_t)(nq*32 + nt*16 + l15)*H + kk + 32);
    }
    half8 af[4];
    #pragma unroll
    for (int mt = 0; mt < 4; ++mt)
      af[mt] = *(const half8*)(hmid + (mh*64 + mt*16 + l15)*264 + kk);
    #pragma unroll
    for (int mt = 0; mt < 4; ++mt)
      #pragma unroll
      for (int nt = 0; nt < 2; ++nt)
        acc2[mt][nt] = __builtin_amdgcn_mfma_f32_16x16x32_f16(af[mt], gcur[nt], acc2[mt][nt], 0, 0, 0);
    #pragma unroll
    for (int nt = 0; nt < 2; ++nt) gcur[nt] = gnxt[nt];
  }

  // epilogue 2: BN (folded b2), optional ReLU, store
  #pragma unroll
  for (int nt = 0; nt < 2; ++nt){
    int n = nq*32 + nt*16 + l15;
    float A = sc[n], B = sh[n];
    #pragma unroll
    for (int mt = 0; mt < 4; ++mt)
      #pragma unroll
      for (int r = 0; r < 4; ++r){
        int row = r0 + mh*64 + mt*16 + quad*4 + r;
        if (row < N){
          float v = acc2[mt][nt][r]*A + B;
          if (relu_out) v = fmaxf(v, 0.f);
          if (fout) fout[(size_t)row*D + n] = v;
          else      hout[(size_t)row*D + n] = (_Float16)v;
        }
      }
  }
}

extern "C" void kernel_launch(void* const* d_in, const int* in_sizes, int n_in,
                              void* d_out, int out_size, void* d_ws, size_t ws_size,
                              hipStream_t stream){
  const int*   x     = (const int*)d_in[0];
  const int*   ei    = (const int*)d_in[1];
  const int*   ea    = (const int*)d_in[2];
  const float* xemb  = (const float*)d_in[3];
  const float* etab  = (const float*)d_in[4];
  const float* w1    = (const float*)d_in[5];
  const float* b1    = (const float*)d_in[6];
  const float* w2    = (const float*)d_in[7];
  const float* b2    = (const float*)d_in[8];
  const float* gamma = (const float*)d_in[9];
  const float* beta  = (const float*)d_in[10];
  const float* mean  = (const float*)d_in[11];
  const float* var   = (const float*)d_in[12];
  float* out = (float*)d_out;

  int N = in_sizes[0] / 2;
  int E = in_sizes[1] / 2;
  int nb = (N + 1023) / 1024;      // scan blocks
  int nbuck = (N + 63) / 64;       // dst buckets

  char* ws = (char*)d_ws;
  size_t off = 0;
  auto alloc = [&](size_t b){ void* p = ws + off; off += (b + 255) & ~(size_t)255; return p; };
  _Float16* h0     = (_Float16*)alloc((size_t)N*D*2);
  _Float16* h1     = (_Float16*)alloc((size_t)N*D*2);   // also aliased as stage (uint2, E*8 <= N*D*2)
  unsigned* packed = (unsigned*)alloc((size_t)(E+8)*4);
  int*      rowptr = (int*)alloc((size_t)(N+1)*4);
  int*      cnt    = (int*)alloc((size_t)N*4);
  int*      bsum   = (int*)alloc((size_t)nb*4);
  int*      bbase  = (int*)alloc((size_t)nb*4);
  int*      bcur   = (int*)alloc((size_t)nbuck*4);
  _Float16* w1h    = (_Float16*)alloc((size_t)5*H*D*2);
  _Float16* w2h    = (_Float16*)alloc((size_t)5*D*H*2);
  float*    comb   = (float*)alloc((size_t)5*10*D*4);
  float*    sc     = (float*)alloc((size_t)5*D*4);
  float*    sh     = (float*)alloc((size_t)5*D*4);
  uint2*    stage  = (uint2*)h1;   // alias: stage dead before h1 is first written (layer 0 output)

  const int* srcp = ei;
  const int* dstp = ei + E;

  hipMemsetAsync(cnt, 0, (size_t)N*4, stream);
  hist_kernel<<<(E+255)/256, 256, 0, stream>>>(dstp, cnt, E);
  scan_part <<<nb, 256, 0, stream>>>(cnt, bsum, N);
  scan_bsums<<<1, 1024, 0, stream>>>(bsum, bbase, rowptr, nb, N);
  scan_emit <<<nb, 256, 0, stream>>>(cnt, bbase, rowptr, N);
  bcur_init <<<(nbuck+255)/256, 256, 0, stream>>>(rowptr, bcur, nbuck);
  bucket_scatter<<<(E+255)/256, 256, 0, stream>>>(srcp, dstp, ea, bcur, stage, E);
  hipMemsetAsync(cnt, 0, (size_t)N*4, stream);
  bucket_emit<<<nbuck, 256, 0, stream>>>(stage, rowptr, cnt, packed, N);
  cvt_weights<<<(5*H*D+255)/256, 256, 0, stream>>>(w1, w2, w1h, w2h, 5*H*D);
  prep_tables<<<5, 128, 0, stream>>>(etab, gamma, beta, mean, var, b2, comb, sc, sh);
  embed_kernel<<<((size_t)N*16+255)/256, 256, 0, stream>>>(x, xemb, h0, N);

  _Float16* hbuf[2] = {h0, h1};
  for (int l = 0; l < 5; ++l){
    int last = (l == 4);
    layer_kernel<<<(N+127)/128, 512, 0, stream>>>(
        hbuf[l & 1], packed, rowptr, comb + (size_t)l*10*D,
        w1h + (size_t)l*H*D, w2h + (size_t)l*D*H,
        b1 + (size_t)l*H, sc + (size_t)l*D, sh + (size_t)l*D,
        last ? (_Float16*)nullptr : hbuf[(l+1) & 1], last ? out : (float*)nullptr,
        N, last ? 0 : 1);
  }
}

// Round 5
// 854.676 us; speedup vs baseline: 2.0950x; 2.0950x over previous
//
#include <hip/hip_runtime.h>

#define D 128
#define H 256

typedef _Float16 half8 __attribute__((ext_vector_type(8)));
typedef _Float16 half2v __attribute__((ext_vector_type(2)));
typedef float floatx4 __attribute__((ext_vector_type(4)));

// ---------------- CSR build ----------------
__global__ void hist_kernel(const int* __restrict__ dst, int* __restrict__ cnt, int E){
  int e = blockIdx.x*256 + threadIdx.x;
  if (e < E) atomicAdd(&cnt[dst[e]], 1);
}

__global__ __launch_bounds__(256) void scan_part(const int* __restrict__ cnt,
                                                 int* __restrict__ bsum, int N){
  int base = blockIdx.x*1024;
  int tid = threadIdx.x;
  int idx = base + tid*4;
  int4 v = {0,0,0,0};
  if (idx + 3 < N) v = *(const int4*)(cnt + idx);
  else {
    if (idx   < N) v.x = cnt[idx];
    if (idx+1 < N) v.y = cnt[idx+1];
    if (idx+2 < N) v.z = cnt[idx+2];
    if (idx+3 < N) v.w = cnt[idx+3];
  }
  int s = v.x + v.y + v.z + v.w;
  #pragma unroll
  for (int off = 32; off > 0; off >>= 1) s += __shfl_down(s, off, 64);
  __shared__ int ws[4];
  int lane = tid & 63, wave = tid >> 6;
  if (lane == 0) ws[wave] = s;
  __syncthreads();
  if (tid == 0) bsum[blockIdx.x] = ws[0] + ws[1] + ws[2] + ws[3];
}

__global__ __launch_bounds__(1024) void scan_bsums(const int* __restrict__ bsum,
                                                   int* __restrict__ bbase,
                                                   int* __restrict__ rowptr, int nb, int N){
  __shared__ int sh[1024];
  int tid = threadIdx.x;
  int v = (tid < nb) ? bsum[tid] : 0;
  sh[tid] = v;
  __syncthreads();
  #pragma unroll
  for (int off = 1; off < 1024; off <<= 1){
    int t = 0;
    if (tid >= off) t = sh[tid - off];
    __syncthreads();
    if (tid >= off) sh[tid] += t;
    __syncthreads();
  }
  if (tid < nb) bbase[tid] = sh[tid] - v;
  if (tid == 0) rowptr[N] = sh[1023];
}

__global__ __launch_bounds__(256) void scan_emit(const int* __restrict__ cnt,
                                                 const int* __restrict__ bbase,
                                                 int* __restrict__ rowptr, int N){
  int base = blockIdx.x*1024;
  int tid = threadIdx.x;
  int idx = base + tid*4;
  int4 v = {0,0,0,0};
  if (idx + 3 < N) v = *(const int4*)(cnt + idx);
  else {
    if (idx   < N) v.x = cnt[idx];
    if (idx+1 < N) v.y = cnt[idx+1];
    if (idx+2 < N) v.z = cnt[idx+2];
    if (idx+3 < N) v.w = cnt[idx+3];
  }
  int s = v.x + v.y + v.z + v.w;
  int lane = tid & 63, wave = tid >> 6;
  int incl = s;
  #pragma unroll
  for (int off = 1; off < 64; off <<= 1){
    int t = __shfl_up(incl, off, 64);
    if (lane >= off) incl += t;
  }
  __shared__ int ws[4];
  if (lane == 63) ws[wave] = incl;
  __syncthreads();
  int woff = 0;
  #pragma unroll
  for (int w = 0; w < 4; ++w) if (w < wave) woff += ws[w];
  int off0 = bbase[blockIdx.x] + woff + (incl - s);
  if (idx   < N) rowptr[idx]   = off0;
  if (idx+1 < N) rowptr[idx+1] = off0 + v.x;
  if (idx+2 < N) rowptr[idx+2] = off0 + v.x + v.y;
  if (idx+3 < N) rowptr[idx+3] = off0 + v.x + v.y + v.z;
}

__global__ void scatter_kernel(const int* __restrict__ src, const int* __restrict__ dst,
                               const int* __restrict__ ea, const int* __restrict__ rowptr,
                               int* __restrict__ cursor, unsigned* __restrict__ packed, int E){
  int e = blockIdx.x*256 + threadIdx.x;
  if (e >= E) return;
  int d = dst[e];
  int pos = rowptr[d] + atomicAdd(&cursor[d], 1);
  unsigned code = (unsigned)(ea[2*e]*3 + ea[2*e+1]);
  packed[pos] = (code << 20) | (unsigned)src[e];
}

// ---------------- input embedding ----------------
__global__ void embed_kernel(const int* __restrict__ x, const float* __restrict__ xemb,
                             _Float16* __restrict__ h, int N){
  int t = blockIdx.x*256 + threadIdx.x;
  if (t >= N*16) return;
  int n = t >> 4, c = (t & 15) * 8;
  int x0 = x[2*n], x1 = x[2*n+1];
  const float* r0 = xemb + (size_t)x0*D + c;
  const float* r1 = xemb + (size_t)(120 + x1)*D + c;
  half8 o;
  #pragma unroll
  for (int j = 0; j < 8; ++j) o[j] = (_Float16)(r0[j] + r1[j]);
  *(half8*)(h + (size_t)n*D + c) = o;
}

// ---------------- per-layer constant tables ----------------
__global__ void prep_tables(const float* __restrict__ etab, const float* __restrict__ gamma,
                            const float* __restrict__ beta, const float* __restrict__ mean,
                            const float* __restrict__ var, const float* __restrict__ b2,
                            float* __restrict__ comb, float* __restrict__ sc, float* __restrict__ sh){
  int l = blockIdx.x, d = threadIdx.x;
  const float* et = etab + (size_t)l*9*D;
  float* cl = comb + (size_t)l*10*D;
  #pragma unroll
  for (int b = 0; b < 3; ++b)
    #pragma unroll
    for (int dd = 0; dd < 3; ++dd)
      cl[(b*3+dd)*D + d] = et[b*D + d] + et[(6+dd)*D + d];
  cl[9*D + d] = et[4*D + d] + et[6*D + d];
  float A = gamma[l*D+d] * rsqrtf(var[l*D+d] + 1e-5f);
  sc[l*D+d] = A;
  sh[l*D+d] = (b2[l*D+d] - mean[l*D+d]) * A + beta[l*D+d];
}

// repack weights fragment-major for coalesced B loads:
// w1f[l][kq][n][8] (kq=k/8, 0..15; n 0..255), w2f[l][kq2][n2][8] (kq2 0..31, n2 0..127)
__global__ void repack_weights(const float* __restrict__ w1, const float* __restrict__ w2,
                               _Float16* __restrict__ w1f, _Float16* __restrict__ w2f, int total){
  int i = blockIdx.x*256 + threadIdx.x;
  if (i >= total) return;                 // total = 5*H*D
  int l = i / (H*D), r = i % (H*D);
  {
    int n = r / D, k = r % D;
    w1f[(size_t)l*H*D + (size_t)(k>>3)*(H*8) + n*8 + (k&7)] = (_Float16)w1[i];
  }
  {
    int n2 = r / H, k2 = r % H;
    w2f[(size_t)l*D*H + (size_t)(k2>>3)*(D*8) + n2*8 + (k2&7)] = (_Float16)w2[i];
  }
}

// ---------------- aggregation: one wave per node, 16 gathers in flight ----------------
__global__ __launch_bounds__(256) void agg_kernel(
    const _Float16* __restrict__ h, const unsigned* __restrict__ packed,
    const int* __restrict__ rowptr, const float* __restrict__ comb,
    _Float16* __restrict__ agg, int N){
  __shared__ float cl[10*D];
  int tid = threadIdx.x;
  for (int i = tid; i < 10*D; i += 256) cl[i] = comb[i];
  __syncthreads();
  int node = __builtin_amdgcn_readfirstlane(blockIdx.x*4 + (tid >> 6)); // wave-uniform
  if (node >= N) return;
  int lane = tid & 63;
  int c = lane * 2;
  half2v hv = *(const half2v*)(h + (size_t)node*D + c);
  float ax = (float)hv.x;
  float ay = (float)hv.y;
  int beg = rowptr[node], end = rowptr[node+1];
  unsigned long long cp = 1ULL << (7*9 - 7*0);  // dummy init; replaced below
  cp = 0;
  // 16 independent gathers in flight; packed loads are wave-uniform (scalarizable)
  for (int j = beg; j < end; j += 16){
    int m = end - j;                       // wave-uniform remaining
    unsigned p[16];
    #pragma unroll
    for (int k = 0; k < 16; ++k) if (k < m) p[k] = packed[j+k];
    half2v v[16];
    #pragma unroll
    for (int k = 0; k < 16; ++k) if (k < m)
      v[k] = *(const half2v*)(h + (size_t)(p[k] & 0xFFFFFu)*D + c);
    #pragma unroll
    for (int k = 0; k < 16; ++k) if (k < m){
      cp += 1ULL << (7*(int)(p[k] >> 20));   // 9 codes x 7-bit counters
      ax += (float)v[k].x;
      ay += (float)v[k].y;
    }
  }
  // self-loop contributes code 9 exactly once
  ax += cl[9*D + c];
  ay += cl[9*D + c + 1];
  #pragma unroll
  for (int cd = 0; cd < 9; ++cd){
    float cnt = (float)(int)((cp >> (7*cd)) & 127);
    ax += cnt * cl[cd*D + c];
    ay += cnt * cl[cd*D + c + 1];
  }
  half2v o; o.x = (_Float16)ax; o.y = (_Float16)ay;
  *(half2v*)(agg + (size_t)node*D + c) = o;
}

// ---------------- fused GIN MLP: stage A->LDS(swizzled), GEMM1+ReLU -> GEMM2+BN --------
// LDS aliased: atile (64x128, swizzled 16B chunks) -> hmid (64x256, swizzled). 32.8 KB.
__global__ __launch_bounds__(256) void mlp_kernel(
    const _Float16* __restrict__ agg, const _Float16* __restrict__ w1f,
    const _Float16* __restrict__ w2f, const float* __restrict__ b1,
    const float* __restrict__ sc, const float* __restrict__ sh,
    _Float16* __restrict__ hout, float* __restrict__ fout,
    int N, int relu_out){
  __shared__ __align__(16) char smem[64*256*2];
  _Float16* atile = (_Float16*)smem;   // row*128 + (c8 ^ (row&15))*8 + (col&7)
  _Float16* hmid  = (_Float16*)smem;   // row*256 + (c8 ^ (row&31))*8 + (col&7)
  int tid = threadIdx.x;
  int wave = tid >> 6, lane = tid & 63;
  int quad = lane >> 4, l15 = lane & 15;
  int r0 = blockIdx.x * 64;

  half8 zf;
  #pragma unroll
  for (int j = 0; j < 8; ++j) zf[j] = (_Float16)0.f;

  // ---- stage A tile [64x128] -> LDS, XOR-swizzled 16B chunks
  #pragma unroll
  for (int i = 0; i < 4; ++i){
    int ci = i*256 + tid;            // 1024 chunks
    int row = ci >> 4, c8 = ci & 15;
    int m = r0 + row;
    half8 v = (m < N) ? *(const half8*)(agg + (size_t)m*D + c8*8) : zf;
    *(half8*)(atile + row*128 + ((c8 ^ (row & 15)) * 8)) = v;
  }
  __syncthreads();

  // ---- GEMM1: C1[64,256] = A x W1^T ; wave owns cols [64w,64w+64); B coalesced frag-major
  floatx4 acc[4][4] = {};
  half8 bcur[4], bnxt[4];
  #pragma unroll
  for (int nt = 0; nt < 4; ++nt)
    bcur[nt] = *(const half8*)(w1f + (size_t)quad*(H*8) + (wave*64 + nt*16 + l15)*8);
  #pragma unroll
  for (int ks = 0; ks < 4; ++ks){
    if (ks < 3){
      #pragma unroll
      for (int nt = 0; nt < 4; ++nt)
        bnxt[nt] = *(const half8*)(w1f + (size_t)((ks+1)*4 + quad)*(H*8) + (wave*64 + nt*16 + l15)*8);
    }
    int c8 = ks*4 + quad;
    half8 af[4];
    #pragma unroll
    for (int mt = 0; mt < 4; ++mt)
      af[mt] = *(const half8*)(atile + (mt*16 + l15)*128 + ((c8 ^ l15) * 8));
    #pragma unroll
    for (int mt = 0; mt < 4; ++mt)
      #pragma unroll
      for (int nt = 0; nt < 4; ++nt)
        acc[mt][nt] = __builtin_amdgcn_mfma_f32_16x16x32_f16(af[mt], bcur[nt], acc[mt][nt], 0, 0, 0);
    #pragma unroll
    for (int nt = 0; nt < 4; ++nt) bcur[nt] = bnxt[nt];
  }
  __syncthreads();   // all waves done reading atile before hmid overwrites it

  // epilogue 1: +b1, ReLU -> hmid (swizzled)
  #pragma unroll
  for (int nt = 0; nt < 4; ++nt){
    int n = wave*64 + nt*16 + l15;
    float bias = b1[n];
    #pragma unroll
    for (int mt = 0; mt < 4; ++mt)
      #pragma unroll
      for (int r = 0; r < 4; ++r){
        int row = mt*16 + quad*4 + r;   // C/D layout: col=lane&15, row=quad*4+reg
        hmid[row*256 + (((n >> 3) ^ (row & 31)) * 8) + (n & 7)] =
            (_Float16)fmaxf(acc[mt][nt][r] + bias, 0.f);
      }
  }
  __syncthreads();

  // ---- GEMM2: C2[64,128] = hmid x W2^T ; wave owns cols [32w,32w+32)
  floatx4 acc2[4][2] = {};
  half8 gcur[2], gnxt[2];
  #pragma unroll
  for (int nt = 0; nt < 2; ++nt)
    gcur[nt] = *(const half8*)(w2f + (size_t)quad*(D*8) + (wave*32 + nt*16 + l15)*8);
  #pragma unroll
  for (int ks = 0; ks < 8; ++ks){
    if (ks < 7){
      #pragma unroll
      for (int nt = 0; nt < 2; ++nt)
        gnxt[nt] = *(const half8*)(w2f + (size_t)((ks+1)*4 + quad)*(D*8) + (wave*32 + nt*16 + l15)*8);
    }
    int c8 = ks*4 + quad;
    half8 af[4];
    #pragma unroll
    for (int mt = 0; mt < 4; ++mt){
      int row = mt*16 + l15;
      af[mt] = *(const half8*)(hmid + row*256 + ((c8 ^ (row & 31)) * 8));
    }
    #pragma unroll
    for (int mt = 0; mt < 4; ++mt)
      #pragma unroll
      for (int nt = 0; nt < 2; ++nt)
        acc2[mt][nt] = __builtin_amdgcn_mfma_f32_16x16x32_f16(af[mt], gcur[nt], acc2[mt][nt], 0, 0, 0);
    #pragma unroll
    for (int nt = 0; nt < 2; ++nt) gcur[nt] = gnxt[nt];
  }

  // epilogue 2: BN (folded b2), optional ReLU, store
  #pragma unroll
  for (int nt = 0; nt < 2; ++nt){
    int n = wave*32 + nt*16 + l15;
    float A = sc[n], B = sh[n];
    #pragma unroll
    for (int mt = 0; mt < 4; ++mt)
      #pragma unroll
      for (int r = 0; r < 4; ++r){
        int row = r0 + mt*16 + quad*4 + r;
        if (row < N){
          float v = acc2[mt][nt][r]*A + B;
          if (relu_out) v = fmaxf(v, 0.f);
          if (fout) fout[(size_t)row*D + n] = v;
          else      hout[(size_t)row*D + n] = (_Float16)v;
        }
      }
  }
}

extern "C" void kernel_launch(void* const* d_in, const int* in_sizes, int n_in,
                              void* d_out, int out_size, void* d_ws, size_t ws_size,
                              hipStream_t stream){
  const int*   x     = (const int*)d_in[0];
  const int*   ei    = (const int*)d_in[1];
  const int*   ea    = (const int*)d_in[2];
  const float* xemb  = (const float*)d_in[3];
  const float* etab  = (const float*)d_in[4];
  const float* w1    = (const float*)d_in[5];
  const float* b1    = (const float*)d_in[6];
  const float* w2    = (const float*)d_in[7];
  const float* b2    = (const float*)d_in[8];
  const float* gamma = (const float*)d_in[9];
  const float* beta  = (const float*)d_in[10];
  const float* mean  = (const float*)d_in[11];
  const float* var   = (const float*)d_in[12];
  float* out = (float*)d_out;

  int N = in_sizes[0] / 2;
  int E = in_sizes[1] / 2;
  int nb = (N + 1023) / 1024;

  char* ws = (char*)d_ws;
  size_t off = 0;
  auto alloc = [&](size_t b){ void* p = ws + off; off += (b + 255) & ~(size_t)255; return p; };
  _Float16* h      = (_Float16*)alloc((size_t)N*D*2);
  _Float16* agg    = (_Float16*)alloc((size_t)N*D*2);
  unsigned* packed = (unsigned*)alloc((size_t)(E+16)*4);
  int*      rowptr = (int*)alloc((size_t)(N+1)*4);
  int*      cnt    = (int*)alloc((size_t)N*4);
  int*      bsum   = (int*)alloc((size_t)nb*4);
  int*      bbase  = (int*)alloc((size_t)nb*4);
  _Float16* w1f    = (_Float16*)alloc((size_t)5*H*D*2);
  _Float16* w2f    = (_Float16*)alloc((size_t)5*D*H*2);
  float*    comb   = (float*)alloc((size_t)5*10*D*4);
  float*    sc     = (float*)alloc((size_t)5*D*4);
  float*    sh     = (float*)alloc((size_t)5*D*4);

  const int* srcp = ei;
  const int* dstp = ei + E;

  hipMemsetAsync(cnt, 0, (size_t)N*4, stream);
  hist_kernel<<<(E+255)/256, 256, 0, stream>>>(dstp, cnt, E);
  scan_part <<<nb, 256, 0, stream>>>(cnt, bsum, N);
  scan_bsums<<<1, 1024, 0, stream>>>(bsum, bbase, rowptr, nb, N);
  scan_emit <<<nb, 256, 0, stream>>>(cnt, bbase, rowptr, N);
  hipMemsetAsync(cnt, 0, (size_t)N*4, stream);
  scatter_kernel<<<(E+255)/256, 256, 0, stream>>>(srcp, dstp, ea, rowptr, cnt, packed, E);
  repack_weights<<<(5*H*D+255)/256, 256, 0, stream>>>(w1, w2, w1f, w2f, 5*H*D);
  prep_tables<<<5, 128, 0, stream>>>(etab, gamma, beta, mean, var, b2, comb, sc, sh);
  embed_kernel<<<((size_t)N*16+255)/256, 256, 0, stream>>>(x, xemb, h, N);

  for (int l = 0; l < 5; ++l){
    agg_kernel<<<(N+3)/4, 256, 0, stream>>>(h, packed, rowptr, comb + (size_t)l*10*D, agg, N);
    int last = (l == 4);
    mlp_kernel<<<(N+63)/64, 256, 0, stream>>>(agg, w1f + (size_t)l*H*D, w2f + (size_t)l*D*H,
        b1 + (size_t)l*H, sc + (size_t)l*D, sh + (size_t)l*D,
        last ? (_Float16*)nullptr : h, last ? out : (float*)nullptr,
        N, last ? 0 : 1);
  }
}